// Round 6
// baseline (52.376 us; speedup 1.0000x reference)
//
#include <hip/hip_runtime.h>
#include <stdint.h>

#define NB   8
#define NN   2048
#define FIN  128
#define FOUT 64
#define MAXS 512

__device__ __forceinline__ uint32_t rotl32(uint32_t x, uint32_t r) {
  return (x << r) | (x >> (32u - r));
}

// JAX threefry2x32 with key = (0, 42)
__device__ __forceinline__ void threefry_0_42(uint32_t x0, uint32_t x1,
                                              uint32_t& o0, uint32_t& o1) {
  const uint32_t k0 = 0u, k1 = 42u;
  const uint32_t k2 = 0x1BD11BDAu ^ k0 ^ k1;
  x0 += k0; x1 += k1;
#define TFR(r) { x0 += x1; x1 = rotl32(x1, r); x1 ^= x0; }
  TFR(13u) TFR(15u) TFR(26u) TFR(6u)   x0 += k1; x1 += k2 + 1u;
  TFR(17u) TFR(29u) TFR(16u) TFR(24u)  x0 += k2; x1 += k0 + 2u;
  TFR(13u) TFR(15u) TFR(26u) TFR(6u)   x0 += k0; x1 += k1 + 3u;
  TFR(17u) TFR(29u) TFR(16u) TFR(24u)  x0 += k1; x1 += k2 + 4u;
  TFR(13u) TFR(15u) TFR(26u) TFR(6u)   x0 += k2; x1 += k0 + 5u;
#undef TFR
  o0 = x0; o1 = x1;
}

// Partitionable threefry: bits = o0^o1 of threefry(key, 0, v); keep iff bit31==0.
__device__ __forceinline__ bool keep_bit(uint32_t v) {
  uint32_t o0, o1;
  threefry_0_42(0u, v, o0, o1);
  return !((o0 ^ o1) >> 31);
}

// Kernel A: Wh = h @ W, Wh1 = Wh@a[:64], Wh2 = Wh@a[64:]
// 4 rows/wave, scalar accumulators (W LDS read amortized x4, no spill risk).
__global__ __launch_bounds__(256) void wh_kernel(
    const float* __restrict__ h, const float* __restrict__ W,
    const float* __restrict__ a, float* __restrict__ Wh,
    float* __restrict__ Wh1, float* __restrict__ Wh2) {
  __shared__ __align__(16) float wLds[FIN * FOUT];   // 32 KB
  __shared__ __align__(16) float hLds[16][FIN];      // 8 KB
  const int t = threadIdx.x;
  const int wv = t >> 6, lane = t & 63;
  const int rbase = blockIdx.x * 16;
  {
    const float4* W4 = reinterpret_cast<const float4*>(W);
    float4* wL4 = reinterpret_cast<float4*>(wLds);
    for (int idx = t; idx < FIN * FOUT / 4; idx += 256) wL4[idx] = W4[idx];
    const float4* h4 = reinterpret_cast<const float4*>(h + (size_t)rbase * FIN);
    float4* hL4 = reinterpret_cast<float4*>(&hLds[0][0]);
    for (int idx = t; idx < 16 * FIN / 4; idx += 256) hL4[idx] = h4[idx];
  }
  __syncthreads();
  const int r0 = wv * 4;
  float acc0 = 0.f, acc1 = 0.f, acc2 = 0.f, acc3 = 0.f;
#pragma unroll 4
  for (int k = 0; k < FIN; ++k) {
    const float w = wLds[k * FOUT + lane];   // lanes consecutive: 2-way, free
    acc0 += hLds[r0 + 0][k] * w;             // broadcasts
    acc1 += hLds[r0 + 1][k] * w;
    acc2 += hLds[r0 + 2][k] * w;
    acc3 += hLds[r0 + 3][k] * w;
  }
  const float a1 = a[lane], a2 = a[FOUT + lane];
  float accs[4] = {acc0, acc1, acc2, acc3};
#pragma unroll
  for (int r = 0; r < 4; ++r) {
    const int row = rbase + r0 + r;
    Wh[(size_t)row * FOUT + lane] = accs[r];
    float x1 = accs[r] * a1, x2 = accs[r] * a2;
#pragma unroll
    for (int off = 32; off >= 1; off >>= 1) {
      x1 += __shfl_xor(x1, off);
      x2 += __shfl_xor(x2, off);
    }
    if (lane == 0) { Wh1[row] = x1; Wh2[row] = x2; }
  }
}

// Kernel B: per block: batch pair (b, b+4), row i.
// Coalescing: each wave-load = 64 lanes x consecutive int4/float4 (1 KB dense).
// phase 1: ww = adj ? Wh2 : -1e30 -> regs; reduce mW (max connected Wh2).
//   monotonicity: e = LR(wh1+Wh2) monotone in Wh2, gap_e >= 0.2*gap_w,
//   so Wh2 < mW-116 => p < 1e-10: skip. row e-max = LR(wh1+mW).
// phase 2: slow path (LR+exp) only where ww > mW-116 (~120/2048); sum s;
//          survivors (p>1e-10, ~3/row) compacted into LDS.
// phase 3: threefry ONLY on compacted survivors.
// phase 4: sparse PV over survivor list.
__global__ __launch_bounds__(256) void attn_kernel(
    const int* __restrict__ adj, const float* __restrict__ Wh,
    const float* __restrict__ Wh1, const float* __restrict__ Wh2,
    float* __restrict__ out) {
  __shared__ float redA[2][4];
  __shared__ int cnt[2];
  __shared__ int   survJ[2][MAXS];   // 4 KB
  __shared__ float survP[2][MAXS];   // 4 KB
  __shared__ float accL[2][4][FOUT]; // 2 KB

  const int i = blockIdx.x & (NN - 1);
  const int b = blockIdx.x >> 11;                 // 0..3
  const int b2 = b + 4;
  const int t = threadIdx.x;
  const int wv = t >> 6, lane = t & 63;

  const float wh1_0 = Wh1[b * NN + i];
  const float wh1_1 = Wh1[b2 * NN + i];
  const size_t adjBase0 = ((size_t)(b * NN) + i) * NN;
  const size_t adjBase1 = ((size_t)(b2 * NN) + i) * NN;
  const int jA = t * 4;            // chunk 0: [0, 1024)
  const int jB = 1024 + t * 4;     // chunk 1: [1024, 2048)

  // issue all 8 vector loads up front (dense 1 KB per wave-instruction)
  const int4   aA0 = *reinterpret_cast<const int4*>(adj + adjBase0 + jA);
  const int4   aB0 = *reinterpret_cast<const int4*>(adj + adjBase0 + jB);
  const int4   aA1 = *reinterpret_cast<const int4*>(adj + adjBase1 + jA);
  const int4   aB1 = *reinterpret_cast<const int4*>(adj + adjBase1 + jB);
  const float4 wA0 = *reinterpret_cast<const float4*>(Wh2 + (size_t)b * NN + jA);
  const float4 wB0 = *reinterpret_cast<const float4*>(Wh2 + (size_t)b * NN + jB);
  const float4 wA1 = *reinterpret_cast<const float4*>(Wh2 + (size_t)b2 * NN + jA);
  const float4 wB1 = *reinterpret_cast<const float4*>(Wh2 + (size_t)b2 * NN + jB);

  float ww0[8], ww1[8];
  ww0[0] = (aA0.x > 0) ? wA0.x : -1.0e30f;
  ww0[1] = (aA0.y > 0) ? wA0.y : -1.0e30f;
  ww0[2] = (aA0.z > 0) ? wA0.z : -1.0e30f;
  ww0[3] = (aA0.w > 0) ? wA0.w : -1.0e30f;
  ww0[4] = (aB0.x > 0) ? wB0.x : -1.0e30f;
  ww0[5] = (aB0.y > 0) ? wB0.y : -1.0e30f;
  ww0[6] = (aB0.z > 0) ? wB0.z : -1.0e30f;
  ww0[7] = (aB0.w > 0) ? wB0.w : -1.0e30f;
  ww1[0] = (aA1.x > 0) ? wA1.x : -1.0e30f;
  ww1[1] = (aA1.y > 0) ? wA1.y : -1.0e30f;
  ww1[2] = (aA1.z > 0) ? wA1.z : -1.0e30f;
  ww1[3] = (aA1.w > 0) ? wA1.w : -1.0e30f;
  ww1[4] = (aB1.x > 0) ? wB1.x : -1.0e30f;
  ww1[5] = (aB1.y > 0) ? wB1.y : -1.0e30f;
  ww1[6] = (aB1.z > 0) ? wB1.z : -1.0e30f;
  ww1[7] = (aB1.w > 0) ? wB1.w : -1.0e30f;

  float mW0 = -3.0e38f, mW1 = -3.0e38f;
#pragma unroll
  for (int e = 0; e < 8; ++e) {
    mW0 = fmaxf(mW0, ww0[e]);
    mW1 = fmaxf(mW1, ww1[e]);
  }
#pragma unroll
  for (int off = 1; off < 64; off <<= 1) {
    mW0 = fmaxf(mW0, __shfl_xor(mW0, off));
    mW1 = fmaxf(mW1, __shfl_xor(mW1, off));
  }
  if (lane == 0) { redA[0][wv] = mW0; redA[1][wv] = mW1; }
  if (t < 2) cnt[t] = 0;
  __syncthreads();
  mW0 = fmaxf(fmaxf(redA[0][0], redA[0][1]), fmaxf(redA[0][2], redA[0][3]));
  mW1 = fmaxf(fmaxf(redA[1][0], redA[1][1]), fmaxf(redA[1][2], redA[1][3]));

  const float me0_arg = wh1_0 + mW0;
  const float me1_arg = wh1_1 + mW1;
  const float me0 = (me0_arg < 0.f) ? 0.2f * me0_arg : me0_arg;  // row max of e
  const float me1 = (me1_arg < 0.f) ? 0.2f * me1_arg : me1_arg;
  const float thr0 = mW0 - 116.f;
  const float thr1 = mW1 - 116.f;

  float s0 = 0.f, s1 = 0.f;
#pragma unroll
  for (int k = 0; k < 8; ++k) {
    const int j = (k < 4) ? (jA + k) : (jB + k - 4);
    if (ww0[k] > thr0) {
      float x = wh1_0 + ww0[k];
      x = (x < 0.f) ? 0.2f * x : x;
      const float p = __expf(x - me0);
      s0 += p;
      if (p > 1e-10f) {
        const int idx = atomicAdd(&cnt[0], 1);
        if (idx < MAXS) { survJ[0][idx] = j; survP[0][idx] = p; }
      }
    }
    if (ww1[k] > thr1) {
      float y = wh1_1 + ww1[k];
      y = (y < 0.f) ? 0.2f * y : y;
      const float p = __expf(y - me1);
      s1 += p;
      if (p > 1e-10f) {
        const int idx = atomicAdd(&cnt[1], 1);
        if (idx < MAXS) { survJ[1][idx] = j; survP[1][idx] = p; }
      }
    }
  }
#pragma unroll
  for (int off = 1; off < 64; off <<= 1) {
    s0 += __shfl_xor(s0, off);
    s1 += __shfl_xor(s1, off);
  }
  if (lane == 0) { redA[0][wv] = s0; redA[1][wv] = s1; }
  __syncthreads();
  s0 = redA[0][0] + redA[0][1] + redA[0][2] + redA[0][3];
  s1 = redA[1][0] + redA[1][1] + redA[1][2] + redA[1][3];
  const float inv0 = 2.0f / s0;   // dropout 1/(1-p)=2 folded in
  const float inv1 = 2.0f / s1;
  const int c0 = min(cnt[0], MAXS), c1 = min(cnt[1], MAXS);

  // phase 3: lazy dropout, only on survivors
  for (int idx = t; idx < c0; idx += 256) {
    const uint32_t v = ((uint32_t)b << 22) | ((uint32_t)i << 11) | (uint32_t)survJ[0][idx];
    survP[0][idx] = keep_bit(v) ? survP[0][idx] * inv0 : 0.f;
  }
  for (int idx = t; idx < c1; idx += 256) {
    const uint32_t v = ((uint32_t)b2 << 22) | ((uint32_t)i << 11) | (uint32_t)survJ[1][idx];
    survP[1][idx] = keep_bit(v) ? survP[1][idx] * inv1 : 0.f;
  }
  __syncthreads();

  // phase 4: sparse PV over survivor list
  float acc0 = 0.f, acc1 = 0.f;
  for (int idx = wv; idx < c0; idx += 4) {
    const float c = survP[0][idx];
    if (c != 0.f)
      acc0 += c * Wh[((size_t)(b * NN + survJ[0][idx])) * FOUT + lane];
  }
  for (int idx = wv; idx < c1; idx += 4) {
    const float c = survP[1][idx];
    if (c != 0.f)
      acc1 += c * Wh[((size_t)(b2 * NN + survJ[1][idx])) * FOUT + lane];
  }
  accL[0][wv][lane] = acc0;
  accL[1][wv][lane] = acc1;
  __syncthreads();
  if (t < 128) {
    const int bb = t >> 6, f = t & 63;
    const float r = accL[bb][0][f] + accL[bb][1][f] + accL[bb][2][f] + accL[bb][3][f];
    const int bo = (bb == 0) ? b : b2;
    out[((size_t)bo * NN + i) * FOUT + f] = r;
  }
}

extern "C" void kernel_launch(void* const* d_in, const int* in_sizes, int n_in,
                              void* d_out, int out_size, void* d_ws, size_t ws_size,
                              hipStream_t stream) {
  const float* h   = (const float*)d_in[0];
  const int*   adj = (const int*)d_in[1];
  const float* W   = (const float*)d_in[2];
  const float* a   = (const float*)d_in[3];
  float* out = (float*)d_out;
  float* ws  = (float*)d_ws;

  float* Wh  = ws;                                 // 16384*64 floats
  float* Wh1 = ws + (size_t)NB * NN * FOUT;        // 16384
  float* Wh2 = Wh1 + NB * NN;                      // 16384

  wh_kernel<<<dim3((NB * NN) / 16), dim3(256), 0, stream>>>(h, W, a, Wh, Wh1, Wh2);
  attn_kernel<<<dim3((NB / 2) * NN), dim3(256), 0, stream>>>(adj, Wh, Wh1, Wh2, out);
}